// Round 6
// baseline (555.646 us; speedup 1.0000x reference)
//
#include <hip/hip_runtime.h>

#define NNODES 50000
#define HEADS 3
#define NBUCK 196          // ceil(50000/256)
#define BCAP  16320        // per-bucket edge capacity (avg 8163)

typedef __attribute__((ext_vector_type(8))) short bf16x8;
typedef __attribute__((ext_vector_type(4))) float f32x4;

__device__ __forceinline__ float wred_sum(float v){
  #pragma unroll
  for (int s = 32; s > 0; s >>= 1) v += __shfl_xor(v, s, 64);
  return v;
}
__device__ __forceinline__ unsigned short f2bf(float x){
  unsigned int u = __float_as_uint(x);
  unsigned int r = (u + 0x7FFFu + ((u >> 16) & 1u)) >> 16;
  return (unsigned short)r;
}

// ---------------- x (fp32) -> bf16, vectorized ----------------
__global__ __launch_bounds__(256) void cvt_bf16_kernel(
    const float* __restrict__ in, unsigned short* __restrict__ outb, int n4)
{
  int i = blockIdx.x * 256 + threadIdx.x;
  if (i >= n4) return;
  float4 v = ((const float4*)in)[i];
  ushort4 o;
  o.x = f2bf(v.x); o.y = f2bf(v.y); o.z = f2bf(v.z); o.w = f2bf(v.w);
  ((ushort4*)outb)[i] = o;
}

// ---------------- W -> MFMA-fragment bf16, with folded el/er columns -------
__global__ __launch_bounds__(256) void prep_b_kernel(
    const float* __restrict__ W, const float* __restrict__ al,
    const float* __restrict__ ar, unsigned short* __restrict__ Bf,
    int K, int NT, int NCf, int F)
{
  int tid = blockIdx.x * 256 + threadIdx.x;
  int total = (K >> 5) * NT * 64;
  if (tid >= total) return;
  int l  = tid & 63;
  int t  = (tid >> 6) % NT;
  int kc = tid / (NT * 64);
  int k0  = kc * 32 + (l >> 4) * 8;
  int col = t * 16 + (l & 15);
  unsigned short o[8];
  #pragma unroll
  for (int j = 0; j < 8; ++j) {
    int k = k0 + j;
    float v = 0.f;
    if (col < NCf) {
      v = W[(size_t)k * NCf + col];
    } else if (col < NCf + 6) {
      int c = col - NCf;
      int h = (c < 3) ? c : c - 3;
      const float* av = ((c < 3) ? al : ar) + h * F;
      const float* wp = W + (size_t)k * NCf + h * F;
      float a = 0.f;
      for (int f = 0; f < F; ++f) a += wp[f] * av[f];
      v = a;
    }
    o[j] = f2bf(v);
  }
  ushort4* dst = (ushort4*)&Bf[(size_t)tid * 8];
  dst[0] = make_ushort4(o[0], o[1], o[2], o[3]);
  dst[1] = make_ushort4(o[4], o[5], o[6], o[7]);
}

// ---------------- MFMA GEMM + el/er epilogue ----------------
__global__ __launch_bounds__(256) void gemm_mfma_kernel(
    const unsigned short* __restrict__ Ab, const unsigned short* __restrict__ Bf,
    unsigned short* __restrict__ Cb, float* __restrict__ elp, float* __restrict__ erp,
    int M, int K, int NT, int NCf)
{
  const int w = threadIdx.x >> 6, l = threadIdx.x & 63;
  const int lrow = l & 15, kg = l >> 4;
  const int r0 = blockIdx.x * 64;
  const bf16x8* Bfv = (const bf16x8*)Bf;

  f32x4 acc[4][4];
  #pragma unroll
  for (int mt = 0; mt < 4; ++mt)
    #pragma unroll
    for (int j = 0; j < 4; ++j)
      acc[mt][j] = (f32x4){0.f, 0.f, 0.f, 0.f};

  const int nkc = K >> 5;
  for (int kc = 0; kc < nkc; ++kc) {
    bf16x8 af[4];
    #pragma unroll
    for (int mt = 0; mt < 4; ++mt) {
      int row = r0 + mt * 16 + lrow;
      bf16x8 z = {0,0,0,0,0,0,0,0};
      af[mt] = z;
      if (row < M)
        af[mt] = *(const bf16x8*)&Ab[(size_t)row * K + kc * 32 + kg * 8];
    }
    #pragma unroll
    for (int j = 0; j < 4; ++j) {
      int tile = w + 4 * j;
      if (tile < NT) {
        bf16x8 bfr = Bfv[((size_t)kc * NT + tile) * 64 + l];
        #pragma unroll
        for (int mt = 0; mt < 4; ++mt)
          acc[mt][j] = __builtin_amdgcn_mfma_f32_16x16x32_bf16(af[mt], bfr, acc[mt][j], 0, 0, 0);
      }
    }
  }
  #pragma unroll
  for (int j = 0; j < 4; ++j) {
    int tile = w + 4 * j;
    if (tile >= NT) continue;
    int c = tile * 16 + lrow;
    #pragma unroll
    for (int mt = 0; mt < 4; ++mt) {
      #pragma unroll
      for (int rr = 0; rr < 4; ++rr) {
        int row = r0 + mt * 16 + kg * 4 + rr;
        if (row >= M) continue;
        float v = acc[mt][j][rr];
        if (c < NCf)            Cb[(size_t)row * NCf + c] = f2bf(v);
        else if (c < NCf + 3)   elp[row * 4 + (c - NCf)] = v;
        else if (c < NCf + 6)   erp[row * 4 + (c - NCf - 3)] = v;
      }
    }
  }
}

// ---------------- CSR build: bucket partition ----------------
__global__ __launch_bounds__(256) void partition_kernel(
    const int* __restrict__ src, const int* __restrict__ dst,
    int* __restrict__ bcur, uint2* __restrict__ ebuf, int E)
{
  __shared__ int hist[NBUCK];
  __shared__ int gbase[NBUCK];
  const int t = threadIdx.x;
  const int e0 = blockIdx.x * 2048;
  for (int i = t; i < NBUCK; i += 256) hist[i] = 0;
  __syncthreads();
  int  b_[8], r_[8];
  uint2 p_[8];
  #pragma unroll
  for (int v = 0; v < 8; ++v) {
    int e = e0 + v * 256 + t;
    b_[v] = -1;
    if (e < E) {
      int s = src[e], d = dst[e];
      p_[v] = make_uint2((unsigned)s, (unsigned)d);
      b_[v] = d >> 8;
      r_[v] = atomicAdd(&hist[b_[v]], 1);
    }
  }
  __syncthreads();
  for (int i = t; i < NBUCK; i += 256) {
    int h = hist[i];
    gbase[i] = h ? atomicAdd(&bcur[i], h) : 0;
  }
  __syncthreads();
  #pragma unroll
  for (int v = 0; v < 8; ++v)
    if (b_[v] >= 0)
      ebuf[(size_t)b_[v] * BCAP + gbase[b_[v]] + r_[v]] = p_[v];
}

// One WG per bucket. Builds off[] and adj with per-dst lists coarsely
// ordered by src (256-row granularity) for gather locality.
__global__ __launch_bounds__(256) void fill_local_kernel(
    const uint2* __restrict__ ebuf, const int* __restrict__ bcur,
    uint2* __restrict__ ebuf2, int* __restrict__ off,
    int* __restrict__ adj, int N)
{
  __shared__ int scur[NBUCK];                 // srcbucket scan/cursors
  __shared__ int lhist[256], loff[256], lcur[256];
  __shared__ int wsum[4], wsum2[4];
  __shared__ int sbase;
  const int b = blockIdx.x;
  const int t = threadIdx.x;
  const int wv = t >> 6, l = t & 63;
  const int cnt = bcur[b];
  const uint2* seg  = ebuf  + (size_t)b * BCAP;
  uint2*       seg2 = ebuf2 + (size_t)b * BCAP;

  // block base = exclusive prefix of bcur over buckets (computed locally)
  {
    int v = (t < NBUCK) ? bcur[t] : 0;
    int x = v;
    #pragma unroll
    for (int s = 1; s < 64; s <<= 1) {
      int y = __shfl_up(x, s, 64);
      if (l >= s) x += y;
    }
    if (l == 63) wsum[wv] = x;
    lhist[t] = 0; lcur[t] = 0;
    if (t < NBUCK) scur[t] = 0;
    __syncthreads();
    int woff = 0;
    #pragma unroll
    for (int k = 0; k < 4; ++k) woff += (k < wv) ? wsum[k] : 0;
    if (t == b) sbase = woff + x - v;
  }
  __syncthreads();

  // pass 1: joint histogram (srcbucket + local dst)
  for (int i = t; i < cnt; i += 256) {
    uint2 p = seg[i];
    atomicAdd(&scur[p.x >> 8], 1);
    atomicAdd(&lhist[p.y & 255], 1);
  }
  __syncthreads();

  // scan both histograms
  {
    int v = (t < NBUCK) ? scur[t] : 0;
    int v2 = lhist[t];
    int x = v, x2 = v2;
    #pragma unroll
    for (int s = 1; s < 64; s <<= 1) {
      int y  = __shfl_up(x,  s, 64);
      int y2 = __shfl_up(x2, s, 64);
      if (l >= s) { x += y; x2 += y2; }
    }
    if (l == 63) { wsum[wv] = x; wsum2[wv] = x2; }
    __syncthreads();
    int woff = 0, woff2 = 0;
    #pragma unroll
    for (int k = 0; k < 4; ++k) {
      woff  += (k < wv) ? wsum[k]  : 0;
      woff2 += (k < wv) ? wsum2[k] : 0;
    }
    if (t < NBUCK) scur[t] = woff + x - v;
    loff[t] = woff2 + x2 - v2;
    int gd = (b << 8) + t;
    if (gd <= N) off[gd] = sbase + loff[t];
  }
  __syncthreads();

  // pass 2: group segment by srcbucket (order within bucket arbitrary)
  for (int i = t; i < cnt; i += 256) {
    uint2 p = seg[i];
    int r = atomicAdd(&scur[p.x >> 8], 1);
    seg2[r] = p;
  }
  __syncthreads();

  // pass 3: chunked-sequential scatter -> per-dst lists coarsely src-sorted
  for (int c0 = 0; c0 < cnt; c0 += 256) {
    int i = c0 + t;
    if (i < cnt) {
      uint2 p = seg2[i];
      int d = p.y & 255;
      int r = atomicAdd(&lcur[d], 1);
      adj[sbase + loff[d] + r] = (int)p.x;
    }
    __syncthreads();
  }
}

// ---------------- aggregation: one wave per dst node, flash-style ----------
__global__ __launch_bounds__(256) void aggregate_kernel(
    const unsigned short* __restrict__ featb, const int* __restrict__ adj,
    const int* __restrict__ off, const float* __restrict__ elp,
    const float* __restrict__ erp, void* __restrict__ outp,
    int N, int F, int mode)
{
  __shared__ float4 pl[4][64];
  int wv = threadIdx.x >> 6, l = threadIdx.x & 63;
  int n  = blockIdx.x * 4 + wv;
  if (n >= N) return;
  const int NC = HEADS * F;
  const unsigned rowbytes = NC * 2;
  int o0 = off[n], d = off[n + 1] - o0;
  float er0 = erp[n * 4 + 0], er1 = erp[n * 4 + 1], er2 = erp[n * 4 + 2];
  const float4* elv = (const float4*)elp;
  const char* fbase = (const char*)featb;
  const int gl = (F == 64) ? 48 : 30;
  const int h  = (F == 64) ? (l >> 4) : (l / 10);
  const unsigned loff2 = (unsigned)l * 8u;
  const float4* plw = pl[wv];

  float m0 = -1e30f, m1 = -1e30f, m2 = -1e30f;
  float s0 = 0.f, s1 = 0.f, s2 = 0.f;
  float4 acc = {0.f, 0.f, 0.f, 0.f};

  for (int base = 0; base < d; base += 64) {
    int i = base + l;
    float x0 = -1e30f, x1 = -1e30f, x2 = -1e30f;
    unsigned boff = 0;
    if (i < d) {
      int ssrc = adj[o0 + i];
      boff = (unsigned)ssrc * rowbytes;
      float4 ev = elv[ssrc];
      x0 = ev.x + er0; x0 = fmaxf(x0, 0.2f * x0);
      x1 = ev.y + er1; x1 = fmaxf(x1, 0.2f * x1);
      x2 = ev.z + er2; x2 = fmaxf(x2, 0.2f * x2);
    }
    float c0 = x0, c1 = x1, c2 = x2;
    #pragma unroll
    for (int o_ = 32; o_ > 0; o_ >>= 1) {
      c0 = fmaxf(c0, __shfl_xor(c0, o_, 64));
      c1 = fmaxf(c1, __shfl_xor(c1, o_, 64));
      c2 = fmaxf(c2, __shfl_xor(c2, o_, 64));
    }
    float M0 = fmaxf(m0, c0), M1 = fmaxf(m1, c1), M2 = fmaxf(m2, c2);
    float r0 = __expf(m0 - M0), r1 = __expf(m1 - M1), r2 = __expf(m2 - M2);
    s0 *= r0; s1 *= r1; s2 *= r2;
    float rh = (h == 0) ? r0 : (h == 1) ? r1 : r2;
    acc.x *= rh; acc.y *= rh; acc.z *= rh; acc.w *= rh;
    m0 = M0; m1 = M1; m2 = M2;
    float p0 = __expf(x0 - M0), p1 = __expf(x1 - M1), p2 = __expf(x2 - M2);
    s0 += p0; s1 += p1; s2 += p2;
    pl[wv][l] = make_float4(__uint_as_float(boff), p0, p1, p2);

    int cnt = min(64, d - base);
    if (l < gl) {
      int e = 0;
      for (; e + 8 <= cnt; e += 8) {
        float4 aa[8];
        uint2  uu[8];
        #pragma unroll
        for (int q = 0; q < 8; ++q) aa[q] = plw[e + q];
        #pragma unroll
        for (int q = 0; q < 8; ++q)
          uu[q] = *(const uint2*)(fbase + (__float_as_uint(aa[q].x) + loff2));
        #pragma unroll
        for (int q = 0; q < 8; ++q) {
          float w0 = (h == 0) ? aa[q].y : (h == 1) ? aa[q].z : aa[q].w;
          acc.x += w0 * __uint_as_float(uu[q].x << 16);
          acc.y += w0 * __uint_as_float(uu[q].x & 0xffff0000u);
          acc.z += w0 * __uint_as_float(uu[q].y << 16);
          acc.w += w0 * __uint_as_float(uu[q].y & 0xffff0000u);
        }
      }
      for (; e < cnt; ++e) {
        float4 a0 = plw[e];
        uint2 u0 = *(const uint2*)(fbase + (__float_as_uint(a0.x) + loff2));
        float w0 = (h == 0) ? a0.y : (h == 1) ? a0.z : a0.w;
        acc.x += w0 * __uint_as_float(u0.x << 16);
        acc.y += w0 * __uint_as_float(u0.x & 0xffff0000u);
        acc.z += w0 * __uint_as_float(u0.y << 16);
        acc.w += w0 * __uint_as_float(u0.y & 0xffff0000u);
      }
    }
  }

  s0 = wred_sum(s0); s1 = wred_sum(s1); s2 = wred_sum(s2);
  float i0 = s0 > 0.f ? 1.f / s0 : 0.f;
  float i1 = s1 > 0.f ? 1.f / s1 : 0.f;
  float i2 = s2 > 0.f ? 1.f / s2 : 0.f;
  float ih = (h == 0) ? i0 : (h == 1) ? i1 : i2;
  acc.x *= ih; acc.y *= ih; acc.z *= ih; acc.w *= ih;

  if (mode == 0) {
    if (l < 48) {
      ushort4 o;
      o.x = f2bf(fmaxf(acc.x, 0.f)); o.y = f2bf(fmaxf(acc.y, 0.f));
      o.z = f2bf(fmaxf(acc.z, 0.f)); o.w = f2bf(fmaxf(acc.w, 0.f));
      *(ushort4*)((unsigned short*)outp + (size_t)n * 192 + l * 4) = o;
    }
  } else {
    float bx = __shfl(acc.x, l + 10, 64), cx = __shfl(acc.x, l + 20, 64);
    float by = __shfl(acc.y, l + 10, 64), cy = __shfl(acc.y, l + 20, 64);
    float bz = __shfl(acc.z, l + 10, 64), cz = __shfl(acc.z, l + 20, 64);
    float bw = __shfl(acc.w, l + 10, 64), cw = __shfl(acc.w, l + 20, 64);
    if (l < 10) {
      float4 o;
      o.x = (acc.x + bx + cx) * (1.f / 3.f);
      o.y = (acc.y + by + cy) * (1.f / 3.f);
      o.z = (acc.z + bz + cz) * (1.f / 3.f);
      o.w = (acc.w + bw + cw) * (1.f / 3.f);
      *(float4*)((float*)outp + (size_t)n * 40 + l * 4) = o;
    }
  }
}

extern "C" void kernel_launch(void* const* d_in, const int* in_sizes, int n_in,
                              void* d_out, int out_size, void* d_ws, size_t ws_size,
                              hipStream_t stream) {
  const float* x   = (const float*)d_in[0];
  const int*   src = (const int*)d_in[1];
  const int*   dst = (const int*)d_in[2];
  const float* W0  = (const float*)d_in[3];
  const float* al0 = (const float*)d_in[4];
  const float* ar0 = (const float*)d_in[5];
  const float* W1  = (const float*)d_in[6];
  const float* al1 = (const float*)d_in[7];
  const float* ar1 = (const float*)d_in[8];
  const float* W2  = (const float*)d_in[9];
  const float* al2 = (const float*)d_in[10];
  const float* ar2 = (const float*)d_in[11];
  const int N = NNODES;
  const int E = in_sizes[1];
  float* out = (float*)d_out;

  char* w = (char*)d_ws;
  unsigned short* xb    = (unsigned short*)w; w += (size_t)N * 256 * 2;  // 25.6MB
  unsigned short* featb = (unsigned short*)w; w += (size_t)N * 192 * 2;  // 19.2MB
  unsigned short* aggb  = (unsigned short*)w; w += (size_t)N * 192 * 2;  // 19.2MB
  unsigned short* Bf    = (unsigned short*)w; w += (size_t)128 * 1024;   // 128KB
  float* elp = (float*)w; w += (size_t)N * 4 * 4;
  float* erp = (float*)w; w += (size_t)N * 4 * 4;
  int* off   = (int*)w;  w += (size_t)(N + 1) * 4;
  int* adj   = (int*)w;  w += (size_t)E * 4;
  int* bcur  = (int*)w;  w += (size_t)NBUCK * 4;
  uint2* ebuf  = (uint2*)xb;     // alias: dead until cvt_bf16 runs
  uint2* ebuf2 = (uint2*)featb;  // alias: spans featb+aggb, dead until layer 0

  // CSR build via bucket partition (all scatters L2-local)
  hipMemsetAsync(bcur, 0, (size_t)NBUCK * 4, stream);
  partition_kernel<<<(E + 2047) / 2048, 256, 0, stream>>>(src, dst, bcur, ebuf, E);
  fill_local_kernel<<<NBUCK, 256, 0, stream>>>(ebuf, bcur, ebuf2, off, adj, N);

  // x -> bf16 (after CSR: xb aliases ebuf)
  cvt_bf16_kernel<<<(N * 256 / 4 + 255) / 256, 256, 0, stream>>>(x, xb, N * 256 / 4);

  int gblk = (N + 63) / 64;
  int ablk = (N + 3) / 4;

  // layer 0: K=256, NT=13 (192 feat cols + tile12 = el/er)
  prep_b_kernel<<<(8 * 13 * 64 + 255) / 256, 256, 0, stream>>>(W0, al0, ar0, Bf, 256, 13, 192, 64);
  gemm_mfma_kernel<<<gblk, 256, 0, stream>>>(xb, Bf, featb, elp, erp, N, 256, 13, 192);
  aggregate_kernel<<<ablk, 256, 0, stream>>>(featb, adj, off, elp, erp, aggb, N, 64, 0);
  // layer 1: K=192, NT=13
  prep_b_kernel<<<(6 * 13 * 64 + 255) / 256, 256, 0, stream>>>(W1, al1, ar1, Bf, 192, 13, 192, 64);
  gemm_mfma_kernel<<<gblk, 256, 0, stream>>>(aggb, Bf, featb, elp, erp, N, 192, 13, 192);
  aggregate_kernel<<<ablk, 256, 0, stream>>>(featb, adj, off, elp, erp, aggb, N, 64, 0);
  // layer 2: K=192, NT=8 (120 feat cols + el/er in cols 120..125 of tile 7)
  prep_b_kernel<<<(6 * 8 * 64 + 255) / 256, 256, 0, stream>>>(W2, al2, ar2, Bf, 192, 8, 120, 40);
  gemm_mfma_kernel<<<gblk, 256, 0, stream>>>(aggb, Bf, featb, elp, erp, N, 192, 8, 120);
  aggregate_kernel<<<ablk, 256, 0, stream>>>(featb, adj, off, elp, erp, out, N, 40, 1);
}